// Round 5
// baseline (544.298 us; speedup 1.0000x reference)
//
#include <hip/hip_runtime.h>

// Problem constants (fixed by the reference file)
constexpr int C_  = 128;
constexpr int D_  = 32;
constexpr int H_  = 64;
constexpr int W_  = 64;
constexpr int PD = 4;
constexpr int PH = 7;
constexpr int PW = 7;
constexpr int SR = 2;          // sampling ratio
constexpr float SCALE = 0.25f; // spatial scale
constexpr int S_ = D_ * H_ * W_;           // 131072 spatial elements
constexpr int BINS_PER_ROI = PD * PH * PW; // 196
constexpr int SLAB = PH * PW;              // 49 bins per (roi, pd) slab

// ---------------------------------------------------------------------------
// Per-axis sampling (matches reference _axis + sample_coords exactly)
// ---------------------------------------------------------------------------
__device__ __forceinline__ void axis2(float start, float extent, int P, int p,
                                      int size, int lo[2], int hi[2],
                                      float w[2], bool v[2]) {
    float bin = extent / (float)P;
#pragma unroll
    for (int u = 0; u < 2; ++u) {
        float t = ((float)(p * SR + u) + 0.5f) / (float)SR;
        float coord = start + t * bin;
        v[u] = (coord >= -1.0f) && (coord <= (float)size);
        float cc = fminf(fmaxf(coord, 0.0f), (float)size - 1.0f);
        float fl = floorf(cc);
        lo[u] = (int)fl;
        hi[u] = min(lo[u] + 1, size - 1);
        w[u] = cc - fl;
    }
}

// float -> bf16 bits (round-to-nearest-even; inputs are finite)
__device__ __forceinline__ unsigned int f2bf(float f) {
    unsigned int u = __float_as_uint(f);
    u += 0x7fffu + ((u >> 16) & 1u);
    return u >> 16;
}

__device__ __forceinline__ float bflo(unsigned int u) {
    return __uint_as_float(u << 16);
}
__device__ __forceinline__ float bfhi(unsigned int u) {
    return __uint_as_float(u & 0xffff0000u);
}

// ---------------------------------------------------------------------------
// Transpose + cast: [N, C, S] f32 -> [N, S, C] bf16.
// 512 threads, 128-s x 128-c tile. Read: one wave covers 512 B contiguous
// per channel. Write: 512 B contiguous per wave. All LDS ops 32-bit.
// ---------------------------------------------------------------------------
__global__ __launch_bounds__(512) void transpose_bf16(
    const float* __restrict__ in, unsigned int* __restrict__ outp) {
    __shared__ unsigned int tileu[128][67]; // [s][cpair] bf16x2
    const int n  = blockIdx.y;
    const int s0 = blockIdx.x * 128;
    const int t  = threadIdx.x;

    const float* src = in + (size_t)n * C_ * S_;
    unsigned int* dst = outp + (size_t)n * (C_ / 2) * S_;

    // Load phase: float4 along S for two adjacent channels; pack to bf16x2.
    {
        const int cp0 = t >> 5;       // 0..15
        const int s4  = (t & 31) * 4; // 0..124
#pragma unroll
        for (int p = 0; p < 4; ++p) {
            const int cp = cp0 + 16 * p; // channel pair 0..63
            const int c = cp * 2;
            const float4 a = *(const float4*)&src[(size_t)c * S_ + (s0 + s4)];
            const float4 b =
                *(const float4*)&src[(size_t)(c + 1) * S_ + (s0 + s4)];
            tileu[s4 + 0][cp] = f2bf(a.x) | (f2bf(b.x) << 16);
            tileu[s4 + 1][cp] = f2bf(a.y) | (f2bf(b.y) << 16);
            tileu[s4 + 2][cp] = f2bf(a.z) | (f2bf(b.z) << 16);
            tileu[s4 + 3][cp] = f2bf(a.w) | (f2bf(b.w) << 16);
        }
    }
    __syncthreads();
    // Store phase: uint2 per lane -> 512 B contiguous per wave.
    {
        const int row0 = t >> 5;      // 0..15
        const int cp2  = (t & 31) * 2;
#pragma unroll
        for (int p = 0; p < 8; ++p) {
            const int s = row0 + 16 * p;
            uint2 v;
            v.x = tileu[s][cp2 + 0];
            v.y = tileu[s][cp2 + 1];
            *(uint2*)&dst[(size_t)(s0 + s) * (C_ / 2) + cp2] = v;
        }
    }
}

// ---------------------------------------------------------------------------
// Main kernel: one block of 512 threads per (roi, pd) slab.
// 32 slot-groups x 16 lanes; each lane accumulates 8 channels (uint4 = 16 B
// bf16x8 loads, 256 B per corner per group). Validity folded into weights:
// no divergent branches, all 8 corner loads of a sample issue back-to-back.
// Results staged in LDS, stored in final [R, C, 196] layout (nontemporal).
// XCD swizzle: all 4 slabs of an ROI share blockIdx%8 -> same XCD L2.
// ---------------------------------------------------------------------------
__global__ __launch_bounds__(512) void roi_align_slab(
    const unsigned short* __restrict__ ft, // [N, D, H, W, C] bf16
    const float* __restrict__ rois,        // [R, 7]
    float* __restrict__ out,               // [R, C, PD, PH, PW]
    int R) {
    __shared__ __align__(16) float tile[SLAB][132];

    int r, pd;
    if ((R & 7) == 0) {
        const int xcd = blockIdx.x & 7;
        const int q = blockIdx.x >> 3;
        pd = q & 3;
        r = ((q >> 2) << 3) + xcd;
    } else {
        r = blockIdx.x >> 2;
        pd = blockIdx.x & 3;
    }

    const int t = threadIdx.x;
    const int grp = t >> 4;       // slot group 0..31
    const int c8 = (t & 15) * 8;  // channel base

    const float* roi = rois + (size_t)r * 7;
    const int b = (int)roi[0];
    const float x1 = roi[1] * SCALE, y1 = roi[2] * SCALE, z1 = roi[3] * SCALE;
    const float x2 = roi[4] * SCALE, y2 = roi[5] * SCALE, z2 = roi[6] * SCALE;
    const float rd = fmaxf(z2 - z1, 1.0f);
    const float rh = fmaxf(y2 - y1, 1.0f);
    const float rw = fmaxf(x2 - x1, 1.0f);

    int zlo[2], zhi[2];
    float wzr[2];
    bool vz[2];
    axis2(z1, rd, PD, pd, D_, zlo, zhi, wzr, vz);
    // Fold validity into z weights.
    float wz0v[2], wz1v[2];
#pragma unroll
    for (int i = 0; i < 2; ++i) {
        wz1v[i] = vz[i] ? wzr[i] : 0.0f;
        wz0v[i] = vz[i] ? 1.0f - wzr[i] : 0.0f;
    }

#pragma unroll 1
    for (int k = 0; k < 2; ++k) {
        const int slot = grp + 32 * k;
        if (slot < SLAB) {
            const int ph = slot / PW;
            const int pw = slot - ph * PW;

            int ylo[2], yhi[2], xlo[2], xhi[2];
            float wyr[2], wxr[2];
            bool vy[2], vx[2];
            axis2(y1, rh, PH, ph, H_, ylo, yhi, wyr, vy);
            axis2(x1, rw, PW, pw, W_, xlo, xhi, wxr, vx);

            float wy0v[2], wy1v[2], wx0v[2], wx1v[2];
#pragma unroll
            for (int j = 0; j < 2; ++j) {
                wy1v[j] = vy[j] ? wyr[j] : 0.0f;
                wy0v[j] = vy[j] ? 1.0f - wyr[j] : 0.0f;
                wx1v[j] = vx[j] ? wxr[j] : 0.0f;
                wx0v[j] = vx[j] ? 1.0f - wxr[j] : 0.0f;
            }

            float acc[8];
#pragma unroll
            for (int q = 0; q < 8; ++q) acc[q] = 0.0f;

#pragma unroll
            for (int i = 0; i < 2; ++i) {
                const float wz0 = wz0v[i], wz1 = wz1v[i];
#pragma unroll
                for (int j = 0; j < 2; ++j) {
                    const float wy0 = wy0v[j], wy1 = wy1v[j];
                    const size_t r00 =
                        (((size_t)b * D_ + zlo[i]) * H_ + ylo[j]) * W_;
                    const size_t r10 =
                        (((size_t)b * D_ + zhi[i]) * H_ + ylo[j]) * W_;
                    const size_t r01 =
                        (((size_t)b * D_ + zlo[i]) * H_ + yhi[j]) * W_;
                    const size_t r11 =
                        (((size_t)b * D_ + zhi[i]) * H_ + yhi[j]) * W_;
#pragma unroll
                    for (int kk = 0; kk < 2; ++kk) {
                        const float wx0 = wx0v[kk], wx1 = wx1v[kk];
                        const size_t xl = xlo[kk], xh = xhi[kk];
                        // 8 corners of this sample point, bf16x8 each.
                        const uint4 u000 =
                            *(const uint4*)&ft[(r00 + xl) * C_ + c8];
                        const uint4 u001 =
                            *(const uint4*)&ft[(r00 + xh) * C_ + c8];
                        const uint4 u010 =
                            *(const uint4*)&ft[(r01 + xl) * C_ + c8];
                        const uint4 u011 =
                            *(const uint4*)&ft[(r01 + xh) * C_ + c8];
                        const uint4 u100 =
                            *(const uint4*)&ft[(r10 + xl) * C_ + c8];
                        const uint4 u101 =
                            *(const uint4*)&ft[(r10 + xh) * C_ + c8];
                        const uint4 u110 =
                            *(const uint4*)&ft[(r11 + xl) * C_ + c8];
                        const uint4 u111 =
                            *(const uint4*)&ft[(r11 + xh) * C_ + c8];
                        const float w000 = wz0 * wy0 * wx0,
                                    w001 = wz0 * wy0 * wx1;
                        const float w010 = wz0 * wy1 * wx0,
                                    w011 = wz0 * wy1 * wx1;
                        const float w100 = wz1 * wy0 * wx0,
                                    w101 = wz1 * wy0 * wx1;
                        const float w110 = wz1 * wy1 * wx0,
                                    w111 = wz1 * wy1 * wx1;
                        const unsigned int p000[4] = {u000.x, u000.y, u000.z,
                                                      u000.w};
                        const unsigned int p001[4] = {u001.x, u001.y, u001.z,
                                                      u001.w};
                        const unsigned int p010[4] = {u010.x, u010.y, u010.z,
                                                      u010.w};
                        const unsigned int p011[4] = {u011.x, u011.y, u011.z,
                                                      u011.w};
                        const unsigned int p100[4] = {u100.x, u100.y, u100.z,
                                                      u100.w};
                        const unsigned int p101[4] = {u101.x, u101.y, u101.z,
                                                      u101.w};
                        const unsigned int p110[4] = {u110.x, u110.y, u110.z,
                                                      u110.w};
                        const unsigned int p111[4] = {u111.x, u111.y, u111.z,
                                                      u111.w};
#pragma unroll
                        for (int m = 0; m < 4; ++m) {
                            acc[2 * m + 0] +=
                                w000 * bflo(p000[m]) + w001 * bflo(p001[m]) +
                                w010 * bflo(p010[m]) + w011 * bflo(p011[m]) +
                                w100 * bflo(p100[m]) + w101 * bflo(p101[m]) +
                                w110 * bflo(p110[m]) + w111 * bflo(p111[m]);
                            acc[2 * m + 1] +=
                                w000 * bfhi(p000[m]) + w001 * bfhi(p001[m]) +
                                w010 * bfhi(p010[m]) + w011 * bfhi(p011[m]) +
                                w100 * bfhi(p100[m]) + w101 * bfhi(p101[m]) +
                                w110 * bfhi(p110[m]) + w111 * bfhi(p111[m]);
                        }
                    }
                }
            }
            const float s = 1.0f / (SR * SR * SR);
            float4 lo4, hi4;
            lo4.x = acc[0] * s; lo4.y = acc[1] * s;
            lo4.z = acc[2] * s; lo4.w = acc[3] * s;
            hi4.x = acc[4] * s; hi4.y = acc[5] * s;
            hi4.z = acc[6] * s; hi4.w = acc[7] * s;
            *(float4*)&tile[slot][c8] = lo4;
            *(float4*)&tile[slot][c8 + 4] = hi4;
        }
    }

    __syncthreads();

    // Store the slab in final layout: out[r][c][pd*49 + o], contiguous o-runs.
    const size_t obase = (size_t)r * C_ * BINS_PER_ROI + (size_t)pd * SLAB;
#pragma unroll 1
    for (int idx = t; idx < C_ * SLAB; idx += 512) {
        const int c = idx / SLAB;
        const int o = idx - c * SLAB;
        __builtin_nontemporal_store(tile[o][c],
                                    &out[obase + (size_t)c * BINS_PER_ROI + o]);
    }
}

// ---------------------------------------------------------------------------
// Fallback: thread-per-output, native layout (tiny ws only).
// ---------------------------------------------------------------------------
__global__ void roi_align_direct(const float* __restrict__ feat,
                                 const float* __restrict__ rois,
                                 float* __restrict__ out, int total) {
    const int tid = blockIdx.x * blockDim.x + threadIdx.x;
    if (tid >= total) return;
    int t = tid;
    const int pw = t % PW; t /= PW;
    const int ph = t % PH; t /= PH;
    const int pd = t % PD; t /= PD;
    const int c = t % C_;  t /= C_;
    const int r = t;

    const float* roi = rois + (size_t)r * 7;
    const int b = (int)roi[0];
    const float x1 = roi[1] * SCALE, y1 = roi[2] * SCALE, z1 = roi[3] * SCALE;
    const float x2 = roi[4] * SCALE, y2 = roi[5] * SCALE, z2 = roi[6] * SCALE;
    const float rd = fmaxf(z2 - z1, 1.0f);
    const float rh = fmaxf(y2 - y1, 1.0f);
    const float rw = fmaxf(x2 - x1, 1.0f);

    int zlo[2], zhi[2], ylo[2], yhi[2], xlo[2], xhi[2];
    float wz[2], wy[2], wx[2];
    bool vz[2], vy[2], vx[2];
    axis2(z1, rd, PD, pd, D_, zlo, zhi, wz, vz);
    axis2(y1, rh, PH, ph, H_, ylo, yhi, wy, vy);
    axis2(x1, rw, PW, pw, W_, xlo, xhi, wx, vx);

    const float* fc = feat + ((size_t)b * C_ + c) * S_;
    float acc = 0.0f;
#pragma unroll
    for (int i = 0; i < 2; ++i) {
        if (!vz[i]) continue;
#pragma unroll
        for (int j = 0; j < 2; ++j) {
            if (!vy[j]) continue;
            const size_t r00 = ((size_t)zlo[i] * H_ + ylo[j]) * W_;
            const size_t r10 = ((size_t)zhi[i] * H_ + ylo[j]) * W_;
            const size_t r01 = ((size_t)zlo[i] * H_ + yhi[j]) * W_;
            const size_t r11 = ((size_t)zhi[i] * H_ + yhi[j]) * W_;
            const float wz1 = wz[i], wz0 = 1.0f - wz1;
            const float wy1 = wy[j], wy0 = 1.0f - wy1;
#pragma unroll
            for (int k = 0; k < 2; ++k) {
                if (!vx[k]) continue;
                const float wx1 = wx[k], wx0 = 1.0f - wx1;
                acc += wz0 * (wy0 * (wx0 * fc[r00 + xlo[k]] + wx1 * fc[r00 + xhi[k]]) +
                              wy1 * (wx0 * fc[r01 + xlo[k]] + wx1 * fc[r01 + xhi[k]])) +
                       wz1 * (wy0 * (wx0 * fc[r10 + xlo[k]] + wx1 * fc[r10 + xhi[k]]) +
                              wy1 * (wx0 * fc[r11 + xlo[k]] + wx1 * fc[r11 + xhi[k]]));
            }
        }
    }
    out[tid] = acc * (1.0f / (SR * SR * SR));
}

extern "C" void kernel_launch(void* const* d_in, const int* in_sizes, int n_in,
                              void* d_out, int out_size, void* d_ws,
                              size_t ws_size, hipStream_t stream) {
    const float* features = (const float*)d_in[0];
    const float* rois = (const float*)d_in[1];
    float* out = (float*)d_out;

    const int R = in_sizes[1] / 7;
    const int N = in_sizes[0] / (C_ * S_);
    const size_t need = (size_t)in_sizes[0] * sizeof(unsigned short);

    if (ws_size >= need) {
        unsigned short* ft = (unsigned short*)d_ws; // [N, D, H, W, C] bf16

        dim3 tg(S_ / 128, N);
        transpose_bf16<<<tg, 512, 0, stream>>>(features, (unsigned int*)ft);

        roi_align_slab<<<R * PD, 512, 0, stream>>>(ft, rois, out, R);
    } else {
        const int total = R * C_ * BINS_PER_ROI;
        roi_align_direct<<<(total + 255) / 256, 256, 0, stream>>>(
            features, rois, out, total);
    }
}

// Round 6
// 264.556 us; speedup vs baseline: 2.0574x; 2.0574x over previous
//
#include <hip/hip_runtime.h>

// Problem constants (fixed by the reference file)
constexpr int C_  = 128;
constexpr int D_  = 32;
constexpr int H_  = 64;
constexpr int W_  = 64;
constexpr int PD = 4;
constexpr int PH = 7;
constexpr int PW = 7;
constexpr int SR = 2;          // sampling ratio
constexpr float SCALE = 0.25f; // spatial scale
constexpr int S_ = D_ * H_ * W_;           // 131072 spatial elements
constexpr int BINS_PER_ROI = PD * PH * PW; // 196
constexpr int SLAB = PH * PW;              // 49 bins per (roi, pd) slab

// ---------------------------------------------------------------------------
// Per-axis sampling (matches reference _axis + sample_coords exactly)
// ---------------------------------------------------------------------------
__device__ __forceinline__ void axis2(float start, float extent, int P, int p,
                                      int size, int lo[2], int hi[2],
                                      float w[2], bool v[2]) {
    float bin = extent / (float)P;
#pragma unroll
    for (int u = 0; u < 2; ++u) {
        float t = ((float)(p * SR + u) + 0.5f) / (float)SR;
        float coord = start + t * bin;
        v[u] = (coord >= -1.0f) && (coord <= (float)size);
        float cc = fminf(fmaxf(coord, 0.0f), (float)size - 1.0f);
        float fl = floorf(cc);
        lo[u] = (int)fl;
        hi[u] = min(lo[u] + 1, size - 1);
        w[u] = cc - fl;
    }
}

// float -> bf16 bits (round-to-nearest-even; inputs are finite)
__device__ __forceinline__ unsigned int f2bf(float f) {
    unsigned int u = __float_as_uint(f);
    u += 0x7fffu + ((u >> 16) & 1u);
    return u >> 16;
}

// unpack 4 bf16 (as uint2) -> float4
__device__ __forceinline__ float4 bf4(uint2 v) {
    float4 f;
    f.x = __uint_as_float(v.x << 16);
    f.y = __uint_as_float(v.x & 0xffff0000u);
    f.z = __uint_as_float(v.y << 16);
    f.w = __uint_as_float(v.y & 0xffff0000u);
    return f;
}

// ---------------------------------------------------------------------------
// Transpose + cast: [N, C, S] f32 -> [N, S, C] bf16.
// 512 threads, 128-s x 128-c tile. Read: one half-wave covers 512 B
// contiguous per channel. Write: 512 B contiguous per wave. LDS all 32-bit.
// ---------------------------------------------------------------------------
__global__ __launch_bounds__(512) void transpose_bf16(
    const float* __restrict__ in, unsigned int* __restrict__ outp) {
    __shared__ unsigned int tileu[128][67]; // [s][cpair] bf16x2
    const int n  = blockIdx.y;
    const int s0 = blockIdx.x * 128;
    const int t  = threadIdx.x;

    const float* src = in + (size_t)n * C_ * S_;
    unsigned int* dst = outp + (size_t)n * (C_ / 2) * S_;

    // Load phase: float4 along S for two adjacent channels; pack to bf16x2.
    {
        const int cp0 = t >> 5;       // 0..15
        const int s4  = (t & 31) * 4; // 0..124
#pragma unroll
        for (int p = 0; p < 4; ++p) {
            const int cp = cp0 + 16 * p; // channel pair 0..63
            const int c = cp * 2;
            const float4 a = *(const float4*)&src[(size_t)c * S_ + (s0 + s4)];
            const float4 b =
                *(const float4*)&src[(size_t)(c + 1) * S_ + (s0 + s4)];
            tileu[s4 + 0][cp] = f2bf(a.x) | (f2bf(b.x) << 16);
            tileu[s4 + 1][cp] = f2bf(a.y) | (f2bf(b.y) << 16);
            tileu[s4 + 2][cp] = f2bf(a.z) | (f2bf(b.z) << 16);
            tileu[s4 + 3][cp] = f2bf(a.w) | (f2bf(b.w) << 16);
        }
    }
    __syncthreads();
    // Store phase: uint2 per lane -> 512 B contiguous per wave.
    {
        const int row0 = t >> 5;      // 0..15
        const int cp2  = (t & 31) * 2;
#pragma unroll
        for (int p = 0; p < 8; ++p) {
            const int s = row0 + 16 * p;
            uint2 v;
            v.x = tileu[s][cp2 + 0];
            v.y = tileu[s][cp2 + 1];
            *(uint2*)&dst[(size_t)(s0 + s) * (C_ / 2) + cp2] = v;
        }
    }
}

// ---------------------------------------------------------------------------
// Main kernel (R4 structure — no register spill): one block of 512 threads
// per (roi, pd) slab. 16 slot-groups x 32 lanes; each lane accumulates 4
// channels (uint2 = 8 B bf16x4 loads, 256 B per corner per group).
// Results staged in LDS, stored in final [R, C, 196] layout (nontemporal).
// XCD swizzle: all 4 slabs of an ROI share blockIdx%8 -> same XCD L2.
// ---------------------------------------------------------------------------
__global__ __launch_bounds__(512) void roi_align_slab(
    const unsigned short* __restrict__ ft, // [N, D, H, W, C] bf16
    const float* __restrict__ rois,        // [R, 7]
    float* __restrict__ out,               // [R, C, PD, PH, PW]
    int R) {
    __shared__ __align__(16) float tile[SLAB][132];

    int r, pd;
    if ((R & 7) == 0) {
        const int xcd = blockIdx.x & 7;
        const int q = blockIdx.x >> 3;
        pd = q & 3;
        r = ((q >> 2) << 3) + xcd;
    } else {
        r = blockIdx.x >> 2;
        pd = blockIdx.x & 3;
    }

    const int t = threadIdx.x;
    const int grp = t >> 5;       // slot group 0..15
    const int c4 = (t & 31) * 4;  // channel base

    const float* roi = rois + (size_t)r * 7;
    const int b = (int)roi[0];
    const float x1 = roi[1] * SCALE, y1 = roi[2] * SCALE, z1 = roi[3] * SCALE;
    const float x2 = roi[4] * SCALE, y2 = roi[5] * SCALE, z2 = roi[6] * SCALE;
    const float rd = fmaxf(z2 - z1, 1.0f);
    const float rh = fmaxf(y2 - y1, 1.0f);
    const float rw = fmaxf(x2 - x1, 1.0f);

    int zlo[2], zhi[2];
    float wz[2];
    bool vz[2];
    axis2(z1, rd, PD, pd, D_, zlo, zhi, wz, vz);

#pragma unroll 1
    for (int k = 0; k < 4; ++k) {
        const int slot = grp + 16 * k;
        if (slot < SLAB) {
            const int ph = slot / PW;
            const int pw = slot - ph * PW;

            int ylo[2], yhi[2], xlo[2], xhi[2];
            float wy[2], wx[2];
            bool vy[2], vx[2];
            axis2(y1, rh, PH, ph, H_, ylo, yhi, wy, vy);
            axis2(x1, rw, PW, pw, W_, xlo, xhi, wx, vx);

            float4 acc = make_float4(0.f, 0.f, 0.f, 0.f);
#pragma unroll
            for (int i = 0; i < 2; ++i) {
                if (!vz[i]) continue;
                const float wz1 = wz[i], wz0 = 1.0f - wz1;
#pragma unroll
                for (int j = 0; j < 2; ++j) {
                    if (!vy[j]) continue;
                    const float wy1 = wy[j], wy0 = 1.0f - wy1;
                    const size_t r00 =
                        (((size_t)b * D_ + zlo[i]) * H_ + ylo[j]) * W_;
                    const size_t r10 =
                        (((size_t)b * D_ + zhi[i]) * H_ + ylo[j]) * W_;
                    const size_t r01 =
                        (((size_t)b * D_ + zlo[i]) * H_ + yhi[j]) * W_;
                    const size_t r11 =
                        (((size_t)b * D_ + zhi[i]) * H_ + yhi[j]) * W_;
#pragma unroll
                    for (int kk = 0; kk < 2; ++kk) {
                        if (!vx[kk]) continue;
                        const float wx1 = wx[kk], wx0 = 1.0f - wx1;
                        const size_t xl = xlo[kk], xh = xhi[kk];
                        const float4 f000 =
                            bf4(*(const uint2*)&ft[(r00 + xl) * C_ + c4]);
                        const float4 f001 =
                            bf4(*(const uint2*)&ft[(r00 + xh) * C_ + c4]);
                        const float4 f010 =
                            bf4(*(const uint2*)&ft[(r01 + xl) * C_ + c4]);
                        const float4 f011 =
                            bf4(*(const uint2*)&ft[(r01 + xh) * C_ + c4]);
                        const float4 f100 =
                            bf4(*(const uint2*)&ft[(r10 + xl) * C_ + c4]);
                        const float4 f101 =
                            bf4(*(const uint2*)&ft[(r10 + xh) * C_ + c4]);
                        const float4 f110 =
                            bf4(*(const uint2*)&ft[(r11 + xl) * C_ + c4]);
                        const float4 f111 =
                            bf4(*(const uint2*)&ft[(r11 + xh) * C_ + c4]);
                        const float w000 = wz0 * wy0 * wx0,
                                    w001 = wz0 * wy0 * wx1;
                        const float w010 = wz0 * wy1 * wx0,
                                    w011 = wz0 * wy1 * wx1;
                        const float w100 = wz1 * wy0 * wx0,
                                    w101 = wz1 * wy0 * wx1;
                        const float w110 = wz1 * wy1 * wx0,
                                    w111 = wz1 * wy1 * wx1;
                        acc.x += w000 * f000.x + w001 * f001.x +
                                 w010 * f010.x + w011 * f011.x +
                                 w100 * f100.x + w101 * f101.x +
                                 w110 * f110.x + w111 * f111.x;
                        acc.y += w000 * f000.y + w001 * f001.y +
                                 w010 * f010.y + w011 * f011.y +
                                 w100 * f100.y + w101 * f101.y +
                                 w110 * f110.y + w111 * f111.y;
                        acc.z += w000 * f000.z + w001 * f001.z +
                                 w010 * f010.z + w011 * f011.z +
                                 w100 * f100.z + w101 * f101.z +
                                 w110 * f110.z + w111 * f111.z;
                        acc.w += w000 * f000.w + w001 * f001.w +
                                 w010 * f010.w + w011 * f011.w +
                                 w100 * f100.w + w101 * f101.w +
                                 w110 * f110.w + w111 * f111.w;
                    }
                }
            }
            const float s = 1.0f / (SR * SR * SR);
            acc.x *= s; acc.y *= s; acc.z *= s; acc.w *= s;
            *(float4*)&tile[slot][c4] = acc;
        }
    }

    __syncthreads();

    // Store the slab in final layout: out[r][c][pd*49 + o], contiguous o-runs.
    const size_t obase = (size_t)r * C_ * BINS_PER_ROI + (size_t)pd * SLAB;
#pragma unroll 1
    for (int idx = t; idx < C_ * SLAB; idx += 512) {
        const int c = idx / SLAB;
        const int o = idx - c * SLAB;
        __builtin_nontemporal_store(tile[o][c],
                                    &out[obase + (size_t)c * BINS_PER_ROI + o]);
    }
}

// ---------------------------------------------------------------------------
// Fallback: thread-per-output, native layout (tiny ws only).
// ---------------------------------------------------------------------------
__global__ void roi_align_direct(const float* __restrict__ feat,
                                 const float* __restrict__ rois,
                                 float* __restrict__ out, int total) {
    const int tid = blockIdx.x * blockDim.x + threadIdx.x;
    if (tid >= total) return;
    int t = tid;
    const int pw = t % PW; t /= PW;
    const int ph = t % PH; t /= PH;
    const int pd = t % PD; t /= PD;
    const int c = t % C_;  t /= C_;
    const int r = t;

    const float* roi = rois + (size_t)r * 7;
    const int b = (int)roi[0];
    const float x1 = roi[1] * SCALE, y1 = roi[2] * SCALE, z1 = roi[3] * SCALE;
    const float x2 = roi[4] * SCALE, y2 = roi[5] * SCALE, z2 = roi[6] * SCALE;
    const float rd = fmaxf(z2 - z1, 1.0f);
    const float rh = fmaxf(y2 - y1, 1.0f);
    const float rw = fmaxf(x2 - x1, 1.0f);

    int zlo[2], zhi[2], ylo[2], yhi[2], xlo[2], xhi[2];
    float wz[2], wy[2], wx[2];
    bool vz[2], vy[2], vx[2];
    axis2(z1, rd, PD, pd, D_, zlo, zhi, wz, vz);
    axis2(y1, rh, PH, ph, H_, ylo, yhi, wy, vy);
    axis2(x1, rw, PW, pw, W_, xlo, xhi, wx, vx);

    const float* fc = feat + ((size_t)b * C_ + c) * S_;
    float acc = 0.0f;
#pragma unroll
    for (int i = 0; i < 2; ++i) {
        if (!vz[i]) continue;
#pragma unroll
        for (int j = 0; j < 2; ++j) {
            if (!vy[j]) continue;
            const size_t r00 = ((size_t)zlo[i] * H_ + ylo[j]) * W_;
            const size_t r10 = ((size_t)zhi[i] * H_ + ylo[j]) * W_;
            const size_t r01 = ((size_t)zlo[i] * H_ + yhi[j]) * W_;
            const size_t r11 = ((size_t)zhi[i] * H_ + yhi[j]) * W_;
            const float wz1 = wz[i], wz0 = 1.0f - wz1;
            const float wy1 = wy[j], wy0 = 1.0f - wy1;
#pragma unroll
            for (int k = 0; k < 2; ++k) {
                if (!vx[k]) continue;
                const float wx1 = wx[k], wx0 = 1.0f - wx1;
                acc += wz0 * (wy0 * (wx0 * fc[r00 + xlo[k]] + wx1 * fc[r00 + xhi[k]]) +
                              wy1 * (wx0 * fc[r01 + xlo[k]] + wx1 * fc[r01 + xhi[k]])) +
                       wz1 * (wy0 * (wx0 * fc[r10 + xlo[k]] + wx1 * fc[r10 + xhi[k]]) +
                              wy1 * (wx0 * fc[r11 + xlo[k]] + wx1 * fc[r11 + xhi[k]]));
            }
        }
    }
    out[tid] = acc * (1.0f / (SR * SR * SR));
}

extern "C" void kernel_launch(void* const* d_in, const int* in_sizes, int n_in,
                              void* d_out, int out_size, void* d_ws,
                              size_t ws_size, hipStream_t stream) {
    const float* features = (const float*)d_in[0];
    const float* rois = (const float*)d_in[1];
    float* out = (float*)d_out;

    const int R = in_sizes[1] / 7;
    const int N = in_sizes[0] / (C_ * S_);
    const size_t need = (size_t)in_sizes[0] * sizeof(unsigned short);

    if (ws_size >= need) {
        unsigned short* ft = (unsigned short*)d_ws; // [N, D, H, W, C] bf16

        dim3 tg(S_ / 128, N);
        transpose_bf16<<<tg, 512, 0, stream>>>(features, (unsigned int*)ft);

        roi_align_slab<<<R * PD, 512, 0, stream>>>(ft, rois, out, R);
    } else {
        const int total = R * C_ * BINS_PER_ROI;
        roi_align_direct<<<(total + 255) / 256, 256, 0, stream>>>(
            features, rois, out, total);
    }
}

// Round 8
// 260.100 us; speedup vs baseline: 2.0927x; 1.0171x over previous
//
#include <hip/hip_runtime.h>

// Problem constants (fixed by the reference file)
constexpr int C_  = 128;
constexpr int D_  = 32;
constexpr int H_  = 64;
constexpr int W_  = 64;
constexpr int PD = 4;
constexpr int PH = 7;
constexpr int PW = 7;
constexpr int SR = 2;          // sampling ratio
constexpr float SCALE = 0.25f; // spatial scale
constexpr int S_ = D_ * H_ * W_;           // 131072 spatial elements
constexpr int BINS_PER_ROI = PD * PH * PW; // 196
constexpr int SLAB = PH * PW;              // 49 bins per (roi, pd) slab

typedef float vf4 __attribute__((ext_vector_type(4))); // native vec for NT builtins

// ---------------------------------------------------------------------------
// Per-axis sampling (matches reference _axis + sample_coords exactly)
// ---------------------------------------------------------------------------
__device__ __forceinline__ void axis2(float start, float extent, int P, int p,
                                      int size, int lo[2], int hi[2],
                                      float w[2], bool v[2]) {
    float bin = extent / (float)P;
#pragma unroll
    for (int u = 0; u < 2; ++u) {
        float t = ((float)(p * SR + u) + 0.5f) / (float)SR;
        float coord = start + t * bin;
        v[u] = (coord >= -1.0f) && (coord <= (float)size);
        float cc = fminf(fmaxf(coord, 0.0f), (float)size - 1.0f);
        float fl = floorf(cc);
        lo[u] = (int)fl;
        hi[u] = min(lo[u] + 1, size - 1);
        w[u] = cc - fl;
    }
}

// float -> bf16 bits (round-to-nearest-even; inputs are finite)
__device__ __forceinline__ unsigned int f2bf(float f) {
    unsigned int u = __float_as_uint(f);
    u += 0x7fffu + ((u >> 16) & 1u);
    return u >> 16;
}

// unpack 4 bf16 (as uint2) -> float4
__device__ __forceinline__ float4 bf4(uint2 v) {
    float4 f;
    f.x = __uint_as_float(v.x << 16);
    f.y = __uint_as_float(v.x & 0xffff0000u);
    f.z = __uint_as_float(v.y << 16);
    f.w = __uint_as_float(v.y & 0xffff0000u);
    return f;
}

// ---------------------------------------------------------------------------
// Transpose + cast: [N, C, S] f32 -> [N, S, C] bf16.
// 256-s x 128-c tile per block: reads are 1 KB contiguous per channel row
// (vs 512 B before -> better DRAM page locality). LDS 64 KB (2 blocks/CU).
// XOR-swizzled LDS layout col = cp ^ ((s>>2)&31): write phase covers all 32
// banks (2-way, free); read phase <=4-way b32 (negligible at this volume).
// ---------------------------------------------------------------------------
__global__ __launch_bounds__(512) void transpose_bf16(
    const float* __restrict__ in, unsigned int* __restrict__ outp) {
    __shared__ unsigned int tileu[256][64]; // [s][swizzled cpair], 64 KB
    const int n  = blockIdx.y;
    const int s0 = blockIdx.x * 256;
    const int t  = threadIdx.x;

    const float* src = in + (size_t)n * C_ * S_;
    unsigned int* dst = outp + (size_t)n * (C_ / 2) * S_;

    // Load phase: 1 KB contiguous per channel row per wave instruction.
    {
        const int sl  = t & 63;  // s quad index 0..63 -> s = 4*sl+q
        const int cp0 = t >> 6;  // 0..7
#pragma unroll
        for (int p = 0; p < 8; ++p) {
            const int cp = cp0 + 8 * p; // channel pair 0..63
            const int c = cp * 2;
            const vf4 a = __builtin_nontemporal_load(
                (const vf4*)&src[(size_t)c * S_ + (s0 + 4 * sl)]);
            const vf4 b = __builtin_nontemporal_load(
                (const vf4*)&src[(size_t)(c + 1) * S_ + (s0 + 4 * sl)]);
            const int col = cp ^ (sl & 31); // (s>>2) == sl for q in 0..3
            tileu[4 * sl + 0][col] = f2bf(a.x) | (f2bf(b.x) << 16);
            tileu[4 * sl + 1][col] = f2bf(a.y) | (f2bf(b.y) << 16);
            tileu[4 * sl + 2][col] = f2bf(a.z) | (f2bf(b.z) << 16);
            tileu[4 * sl + 3][col] = f2bf(a.w) | (f2bf(b.w) << 16);
        }
    }
    __syncthreads();
    // Store phase: 512 B contiguous per wave (2 rows x 256 B).
    {
        const int cp2   = (t & 31) * 2; // even logical col 0..62
        const int rbase = t >> 5;       // 0..15
#pragma unroll
        for (int it = 0; it < 16; ++it) {
            const int s = rbase + 16 * it;
            const int w = (s >> 2) & 31;
            uint2 v;
            v.x = tileu[s][cp2 ^ w];
            v.y = tileu[s][(cp2 + 1) ^ w];
            *(uint2*)&dst[(size_t)(s0 + s) * (C_ / 2) + cp2] = v;
        }
    }
}

// ---------------------------------------------------------------------------
// Main kernel (R4/R6 structure — no register spill): one block of 512
// threads per (roi, pd) slab. 16 slot-groups x 32 lanes; each lane
// accumulates 4 channels (uint2 = 8 B bf16x4 loads, 256 B per corner per
// group). Results staged in LDS, stored in final [R, C, 196] layout.
// XCD swizzle: all 4 slabs of an ROI share blockIdx%8 -> same XCD L2.
// ---------------------------------------------------------------------------
__global__ __launch_bounds__(512) void roi_align_slab(
    const unsigned short* __restrict__ ft, // [N, D, H, W, C] bf16
    const float* __restrict__ rois,        // [R, 7]
    float* __restrict__ out,               // [R, C, PD, PH, PW]
    int R) {
    __shared__ __align__(16) float tile[SLAB][132];

    int r, pd;
    if ((R & 7) == 0) {
        const int xcd = blockIdx.x & 7;
        const int q = blockIdx.x >> 3;
        pd = q & 3;
        r = ((q >> 2) << 3) + xcd;
    } else {
        r = blockIdx.x >> 2;
        pd = blockIdx.x & 3;
    }

    const int t = threadIdx.x;
    const int grp = t >> 5;       // slot group 0..15
    const int c4 = (t & 31) * 4;  // channel base

    const float* roi = rois + (size_t)r * 7;
    const int b = (int)roi[0];
    const float x1 = roi[1] * SCALE, y1 = roi[2] * SCALE, z1 = roi[3] * SCALE;
    const float x2 = roi[4] * SCALE, y2 = roi[5] * SCALE, z2 = roi[6] * SCALE;
    const float rd = fmaxf(z2 - z1, 1.0f);
    const float rh = fmaxf(y2 - y1, 1.0f);
    const float rw = fmaxf(x2 - x1, 1.0f);

    int zlo[2], zhi[2];
    float wz[2];
    bool vz[2];
    axis2(z1, rd, PD, pd, D_, zlo, zhi, wz, vz);

#pragma unroll 1
    for (int k = 0; k < 4; ++k) {
        const int slot = grp + 16 * k;
        if (slot < SLAB) {
            const int ph = slot / PW;
            const int pw = slot - ph * PW;

            int ylo[2], yhi[2], xlo[2], xhi[2];
            float wy[2], wx[2];
            bool vy[2], vx[2];
            axis2(y1, rh, PH, ph, H_, ylo, yhi, wy, vy);
            axis2(x1, rw, PW, pw, W_, xlo, xhi, wx, vx);

            float4 acc = make_float4(0.f, 0.f, 0.f, 0.f);
#pragma unroll
            for (int i = 0; i < 2; ++i) {
                if (!vz[i]) continue;
                const float wz1 = wz[i], wz0 = 1.0f - wz1;
#pragma unroll
                for (int j = 0; j < 2; ++j) {
                    if (!vy[j]) continue;
                    const float wy1 = wy[j], wy0 = 1.0f - wy1;
                    const size_t r00 =
                        (((size_t)b * D_ + zlo[i]) * H_ + ylo[j]) * W_;
                    const size_t r10 =
                        (((size_t)b * D_ + zhi[i]) * H_ + ylo[j]) * W_;
                    const size_t r01 =
                        (((size_t)b * D_ + zlo[i]) * H_ + yhi[j]) * W_;
                    const size_t r11 =
                        (((size_t)b * D_ + zhi[i]) * H_ + yhi[j]) * W_;
#pragma unroll
                    for (int kk = 0; kk < 2; ++kk) {
                        if (!vx[kk]) continue;
                        const float wx1 = wx[kk], wx0 = 1.0f - wx1;
                        const size_t xl = xlo[kk], xh = xhi[kk];
                        const float4 f000 =
                            bf4(*(const uint2*)&ft[(r00 + xl) * C_ + c4]);
                        const float4 f001 =
                            bf4(*(const uint2*)&ft[(r00 + xh) * C_ + c4]);
                        const float4 f010 =
                            bf4(*(const uint2*)&ft[(r01 + xl) * C_ + c4]);
                        const float4 f011 =
                            bf4(*(const uint2*)&ft[(r01 + xh) * C_ + c4]);
                        const float4 f100 =
                            bf4(*(const uint2*)&ft[(r10 + xl) * C_ + c4]);
                        const float4 f101 =
                            bf4(*(const uint2*)&ft[(r10 + xh) * C_ + c4]);
                        const float4 f110 =
                            bf4(*(const uint2*)&ft[(r11 + xl) * C_ + c4]);
                        const float4 f111 =
                            bf4(*(const uint2*)&ft[(r11 + xh) * C_ + c4]);
                        const float w000 = wz0 * wy0 * wx0,
                                    w001 = wz0 * wy0 * wx1;
                        const float w010 = wz0 * wy1 * wx0,
                                    w011 = wz0 * wy1 * wx1;
                        const float w100 = wz1 * wy0 * wx0,
                                    w101 = wz1 * wy0 * wx1;
                        const float w110 = wz1 * wy1 * wx0,
                                    w111 = wz1 * wy1 * wx1;
                        acc.x += w000 * f000.x + w001 * f001.x +
                                 w010 * f010.x + w011 * f011.x +
                                 w100 * f100.x + w101 * f101.x +
                                 w110 * f110.x + w111 * f111.x;
                        acc.y += w000 * f000.y + w001 * f001.y +
                                 w010 * f010.y + w011 * f011.y +
                                 w100 * f100.y + w101 * f101.y +
                                 w110 * f110.y + w111 * f111.y;
                        acc.z += w000 * f000.z + w001 * f001.z +
                                 w010 * f010.z + w011 * f011.z +
                                 w100 * f100.z + w101 * f101.z +
                                 w110 * f110.z + w111 * f111.z;
                        acc.w += w000 * f000.w + w001 * f001.w +
                                 w010 * f010.w + w011 * f011.w +
                                 w100 * f100.w + w101 * f101.w +
                                 w110 * f110.w + w111 * f111.w;
                    }
                }
            }
            const float s = 1.0f / (SR * SR * SR);
            acc.x *= s; acc.y *= s; acc.z *= s; acc.w *= s;
            *(float4*)&tile[slot][c4] = acc;
        }
    }

    __syncthreads();

    // Store the slab in final layout: out[r][c][pd*49 + o], contiguous o-runs.
    const size_t obase = (size_t)r * C_ * BINS_PER_ROI + (size_t)pd * SLAB;
#pragma unroll 1
    for (int idx = t; idx < C_ * SLAB; idx += 512) {
        const int c = idx / SLAB;
        const int o = idx - c * SLAB;
        __builtin_nontemporal_store(tile[o][c],
                                    &out[obase + (size_t)c * BINS_PER_ROI + o]);
    }
}

// ---------------------------------------------------------------------------
// Fallback: thread-per-output, native layout (tiny ws only).
// ---------------------------------------------------------------------------
__global__ void roi_align_direct(const float* __restrict__ feat,
                                 const float* __restrict__ rois,
                                 float* __restrict__ out, int total) {
    const int tid = blockIdx.x * blockDim.x + threadIdx.x;
    if (tid >= total) return;
    int t = tid;
    const int pw = t % PW; t /= PW;
    const int ph = t % PH; t /= PH;
    const int pd = t % PD; t /= PD;
    const int c = t % C_;  t /= C_;
    const int r = t;

    const float* roi = rois + (size_t)r * 7;
    const int b = (int)roi[0];
    const float x1 = roi[1] * SCALE, y1 = roi[2] * SCALE, z1 = roi[3] * SCALE;
    const float x2 = roi[4] * SCALE, y2 = roi[5] * SCALE, z2 = roi[6] * SCALE;
    const float rd = fmaxf(z2 - z1, 1.0f);
    const float rh = fmaxf(y2 - y1, 1.0f);
    const float rw = fmaxf(x2 - x1, 1.0f);

    int zlo[2], zhi[2], ylo[2], yhi[2], xlo[2], xhi[2];
    float wz[2], wy[2], wx[2];
    bool vz[2], vy[2], vx[2];
    axis2(z1, rd, PD, pd, D_, zlo, zhi, wz, vz);
    axis2(y1, rh, PH, ph, H_, ylo, yhi, wy, vy);
    axis2(x1, rw, PW, pw, W_, xlo, xhi, wx, vx);

    const float* fc = feat + ((size_t)b * C_ + c) * S_;
    float acc = 0.0f;
#pragma unroll
    for (int i = 0; i < 2; ++i) {
        if (!vz[i]) continue;
#pragma unroll
        for (int j = 0; j < 2; ++j) {
            if (!vy[j]) continue;
            const size_t r00 = ((size_t)zlo[i] * H_ + ylo[j]) * W_;
            const size_t r10 = ((size_t)zhi[i] * H_ + ylo[j]) * W_;
            const size_t r01 = ((size_t)zlo[i] * H_ + yhi[j]) * W_;
            const size_t r11 = ((size_t)zhi[i] * H_ + yhi[j]) * W_;
            const float wz1 = wz[i], wz0 = 1.0f - wz1;
            const float wy1 = wy[j], wy0 = 1.0f - wy1;
#pragma unroll
            for (int k = 0; k < 2; ++k) {
                if (!vx[k]) continue;
                const float wx1 = wx[k], wx0 = 1.0f - wx1;
                acc += wz0 * (wy0 * (wx0 * fc[r00 + xlo[k]] + wx1 * fc[r00 + xhi[k]]) +
                              wy1 * (wx0 * fc[r01 + xlo[k]] + wx1 * fc[r01 + xhi[k]])) +
                       wz1 * (wy0 * (wx0 * fc[r10 + xlo[k]] + wx1 * fc[r10 + xhi[k]]) +
                              wy1 * (wx0 * fc[r11 + xlo[k]] + wx1 * fc[r11 + xhi[k]]));
            }
        }
    }
    out[tid] = acc * (1.0f / (SR * SR * SR));
}

extern "C" void kernel_launch(void* const* d_in, const int* in_sizes, int n_in,
                              void* d_out, int out_size, void* d_ws,
                              size_t ws_size, hipStream_t stream) {
    const float* features = (const float*)d_in[0];
    const float* rois = (const float*)d_in[1];
    float* out = (float*)d_out;

    const int R = in_sizes[1] / 7;
    const int N = in_sizes[0] / (C_ * S_);
    const size_t need = (size_t)in_sizes[0] * sizeof(unsigned short);

    if (ws_size >= need) {
        unsigned short* ft = (unsigned short*)d_ws; // [N, D, H, W, C] bf16

        dim3 tg(S_ / 256, N);
        transpose_bf16<<<tg, 512, 0, stream>>>(features, (unsigned int*)ft);

        roi_align_slab<<<R * PD, 512, 0, stream>>>(ft, rois, out, R);
    } else {
        const int total = R * C_ * BINS_PER_ROI;
        roi_align_direct<<<(total + 255) / 256, 256, 0, stream>>>(
            features, rois, out, total);
    }
}